// Round 1
// baseline (1946.847 us; speedup 1.0000x reference)
//
#include <hip/hip_runtime.h>
#include <math.h>

#define HIDDEN 4096
#define NH 32
#define NKV 8
#define HD 128
#define BBATCH 2
#define SEQ 2048
#define BS 4096   // BBATCH*SEQ

typedef __attribute__((ext_vector_type(8))) short short8;
typedef __attribute__((ext_vector_type(4))) float f32x4;

__device__ __forceinline__ unsigned short f2bf(float f) {
  union { float f; unsigned int u; } v; v.f = f;
  unsigned int r = v.u + 0x7fffu + ((v.u >> 16) & 1u);
  return (unsigned short)(r >> 16);
}
__device__ __forceinline__ float bf2f(unsigned short u) {
  union { unsigned int u; float f; } v; v.u = ((unsigned int)u) << 16;
  return v.f;
}

// ---------------- fp32 -> bf16 cast (vectorized) ----------------
__global__ void cast_f32_bf16(const float* __restrict__ in, unsigned short* __restrict__ out) {
  int i = (blockIdx.x * blockDim.x + threadIdx.x) * 4;
  float4 f = *(const float4*)(in + i);
  ushort4 u;
  u.x = f2bf(f.x); u.y = f2bf(f.y); u.z = f2bf(f.z); u.w = f2bf(f.w);
  *(ushort4*)(out + i) = u;
}

// ---------------- GEMM: C[M,N] = A[M,K] * Bm[N,K]^T  (bf16 in, fp32 acc) ----------------
// 64x64 block tile, 4 waves, each wave 16 rows x 64 cols. LDS stride 40 (2-way conflict only, 16B aligned).
template<int OUT_F32>
__global__ __launch_bounds__(256) void gemm_bt(const unsigned short* __restrict__ A,
                                               const unsigned short* __restrict__ Bm,
                                               void* __restrict__ Cc,
                                               int M, int N, int K) {
  __shared__ unsigned short As[64 * 40];
  __shared__ unsigned short Bs[64 * 40];
  int t = threadIdx.x;
  int wave = t >> 6, lane = t & 63;
  int lm = lane & 15, quad = lane >> 4;
  int m0 = blockIdx.y * 64, n0 = blockIdx.x * 64;
  int srow = t >> 2, scol = (t & 3) * 8;
  f32x4 acc[4] = {};
  const unsigned short* ag = A + (size_t)(m0 + srow) * K + scol;
  const unsigned short* bg = Bm + (size_t)(n0 + srow) * K + scol;
  for (int k0 = 0; k0 < K; k0 += 32) {
    __syncthreads();
    *(uint4*)&As[srow * 40 + scol] = *(const uint4*)(ag + k0);
    *(uint4*)&Bs[srow * 40 + scol] = *(const uint4*)(bg + k0);
    __syncthreads();
    short8 af = *(const short8*)&As[(wave * 16 + lm) * 40 + quad * 8];
#pragma unroll
    for (int nt = 0; nt < 4; nt++) {
      short8 bfr = *(const short8*)&Bs[(nt * 16 + lm) * 40 + quad * 8];
      acc[nt] = __builtin_amdgcn_mfma_f32_16x16x32_bf16(af, bfr, acc[nt], 0, 0, 0);
    }
  }
#pragma unroll
  for (int nt = 0; nt < 4; nt++) {
#pragma unroll
    for (int r = 0; r < 4; r++) {
      size_t row = m0 + wave * 16 + quad * 4 + r;   // C/D: row = quad*4+reg (m89/m91 verified)
      size_t col = n0 + nt * 16 + lm;               //      col = lane&15
      if (OUT_F32) ((float*)Cc)[row * N + col] = acc[nt][r];
      else ((unsigned short*)Cc)[row * N + col] = f2bf(acc[nt][r]);
    }
  }
}

// ---------------- RoPE in-place on bf16 [rows, nheads, 128] ----------------
__global__ void rope_kernel(unsigned short* __restrict__ x, const int* __restrict__ pos_ids, int nheads) {
  int idx = blockIdx.x * blockDim.x + threadIdx.x;
  int j = idx & 63;
  int h = (idx >> 6) % nheads;
  int row = idx / (64 * nheads);
  int s = row & (SEQ - 1);
  float p = (float)pos_ids[s];
  // inv_freq = 10000^(-j/64) = 2^(-j*log2(10000)/64)
  float inv = exp2f(-(float)j * (13.287712379549449f / 64.0f));
  float f = p * inv;
  float c = cosf(f), sn = sinf(f);
  unsigned short* ptr = x + (size_t)row * (nheads * HD) + h * HD;
  float x1 = bf2f(ptr[j]), x2 = bf2f(ptr[j + 64]);
  ptr[j]      = f2bf(x1 * c - x2 * sn);
  ptr[j + 64] = f2bf(x2 * c + x1 * sn);
}

// ---------------- V transpose: [B,S,NKV,HD] -> [B,NKV,HD,S] ----------------
__global__ void transpose_v(const unsigned short* __restrict__ v, unsigned short* __restrict__ vt) {
  int idx = blockIdx.x * blockDim.x + threadIdx.x;
  int s = idx & (SEQ - 1);
  int d = (idx >> 11) & (HD - 1);
  int kv = (idx >> 18) & (NKV - 1);
  int b = idx >> 21;
  vt[idx] = v[(((size_t)(b * SEQ + s)) * NKV + kv) * HD + d];
}

// ---------------- Flash attention: per-wave 16 q-rows, full online softmax over S ----------------
__global__ __launch_bounds__(256) void attn_kernel(const unsigned short* __restrict__ Q,   // [B,S,NH*HD]
                                                   const unsigned short* __restrict__ Kb,  // [B,S,NKV*HD]
                                                   const unsigned short* __restrict__ Vt,  // [B,NKV,HD,S]
                                                   unsigned short* __restrict__ O) {       // [B,S,NH*HD]
  __shared__ unsigned short Plds[4][16 * 40];
  int t = threadIdx.x, wave = t >> 6, lane = t & 63;
  int lm = lane & 15, quad = lane >> 4;
  int blk = blockIdx.x;
  int qt4 = blk & 31;          // 32 groups of 64 q rows
  int h = (blk >> 5) & 31;
  int b = blk >> 10;
  int kv = h >> 2;
  int qs0 = qt4 * 64 + wave * 16;
  const float scale = 0.08838834764831845f;  // 1/sqrt(128)

  // Q fragments (A-operand: m=lane&15, k=quad*8+j), 4 chunks of K=32 over d=128
  short8 aq[4];
  const unsigned short* qbase = Q + ((size_t)(b * SEQ + qs0 + lm)) * HIDDEN + h * HD;
#pragma unroll
  for (int kk = 0; kk < 4; kk++)
    aq[kk] = *(const short8*)(qbase + kk * 32 + quad * 8);

  f32x4 acc[8] = {};     // O accum, 8 d-subtiles of 16, C-layout
  float mrow[4] = {-1e30f, -1e30f, -1e30f, -1e30f};
  float lrow[4] = {0.f, 0.f, 0.f, 0.f};
  const unsigned short* kbase = Kb + ((size_t)b * SEQ) * (NKV * HD) + kv * HD;
  const unsigned short* vbase = Vt + ((size_t)(b * NKV + kv)) * HD * SEQ;

  for (int kblk = 0; kblk < SEQ; kblk += 32) {
    // S = Q K^T for 32 keys: two 16-col C tiles
    f32x4 s0 = {}, s1 = {};
#pragma unroll
    for (int kk = 0; kk < 4; kk++) {
      short8 b0 = *(const short8*)(kbase + (size_t)(kblk + lm) * (NKV * HD) + kk * 32 + quad * 8);
      short8 b1 = *(const short8*)(kbase + (size_t)(kblk + 16 + lm) * (NKV * HD) + kk * 32 + quad * 8);
      s0 = __builtin_amdgcn_mfma_f32_16x16x32_bf16(aq[kk], b0, s0, 0, 0, 0);
      s1 = __builtin_amdgcn_mfma_f32_16x16x32_bf16(aq[kk], b1, s1, 0, 0, 0);
    }
    // online softmax update (rows = quad*4+r, cols across the 16 lanes of the quad-group)
    float p0[4], p1[4], alpha[4];
#pragma unroll
    for (int r = 0; r < 4; r++) {
      float v = fmaxf(s0[r], s1[r]) * scale;
      v = fmaxf(v, __shfl_xor(v, 1));
      v = fmaxf(v, __shfl_xor(v, 2));
      v = fmaxf(v, __shfl_xor(v, 4));
      v = fmaxf(v, __shfl_xor(v, 8));
      float nm = fmaxf(mrow[r], v);
      alpha[r] = expf(mrow[r] - nm);
      p0[r] = expf(s0[r] * scale - nm);
      p1[r] = expf(s1[r] * scale - nm);
      float rs = p0[r] + p1[r];
      rs += __shfl_xor(rs, 1);
      rs += __shfl_xor(rs, 2);
      rs += __shfl_xor(rs, 4);
      rs += __shfl_xor(rs, 8);
      lrow[r] = lrow[r] * alpha[r] + rs;
      mrow[r] = nm;
    }
#pragma unroll
    for (int tt = 0; tt < 8; tt++) {
#pragma unroll
      for (int r = 0; r < 4; r++) acc[tt][r] *= alpha[r];
    }
    // P: C-layout -> LDS -> A-layout (m120 pattern). Per-wave buffer.
    unsigned short* pl = Plds[wave];
#pragma unroll
    for (int r = 0; r < 4; r++) {
      pl[(quad * 4 + r) * 40 + lm] = f2bf(p0[r]);
      pl[(quad * 4 + r) * 40 + 16 + lm] = f2bf(p1[r]);
    }
    __syncthreads();
    short8 ap = *(const short8*)&pl[lm * 40 + quad * 8];
    // O += P * V  (B-operand from Vt: n=d=tt*16+lm, k=key=quad*8+j, 16B contiguous)
#pragma unroll
    for (int tt = 0; tt < 8; tt++) {
      short8 bv = *(const short8*)(vbase + (size_t)(tt * 16 + lm) * SEQ + kblk + quad * 8);
      acc[tt] = __builtin_amdgcn_mfma_f32_16x16x32_bf16(ap, bv, acc[tt], 0, 0, 0);
    }
    __syncthreads();
  }
  // epilogue: normalize and store bf16 to [B,S,NH*HD]
#pragma unroll
  for (int r = 0; r < 4; r++) {
    float inv = 1.0f / lrow[r];
    int row = qs0 + quad * 4 + r;
    unsigned short* op = O + ((size_t)(b * SEQ + row)) * HIDDEN + h * HD;
#pragma unroll
    for (int tt = 0; tt < 8; tt++)
      op[tt * 16 + lm] = f2bf(acc[tt][r] * inv);
  }
}

extern "C" void kernel_launch(void* const* d_in, const int* in_sizes, int n_in,
                              void* d_out, int out_size, void* d_ws, size_t ws_size,
                              hipStream_t stream) {
  const float* hidden = (const float*)d_in[0];
  const int*   pos    = (const int*)d_in[1];
  const float* Wq     = (const float*)d_in[2];
  const float* Wk     = (const float*)d_in[3];
  const float* Wv     = (const float*)d_in[4];
  const float* Wo     = (const float*)d_in[5];

  char* ws = (char*)d_ws;
  unsigned short* hx = (unsigned short*)ws;  ws += (size_t)BS * HIDDEN * 2;        // 33.5MB
  unsigned short* wq = (unsigned short*)ws;  ws += (size_t)HIDDEN * HIDDEN * 2;    // 33.5MB
  unsigned short* wk = (unsigned short*)ws;  ws += (size_t)1024 * HIDDEN * 2;      // 8.4MB
  unsigned short* wv = (unsigned short*)ws;  ws += (size_t)1024 * HIDDEN * 2;      // 8.4MB
  unsigned short* wo = (unsigned short*)ws;  ws += (size_t)HIDDEN * HIDDEN * 2;    // 33.5MB
  unsigned short* qb = (unsigned short*)ws;  ws += (size_t)BS * HIDDEN * 2;        // 33.5MB
  unsigned short* kbf = (unsigned short*)ws; ws += (size_t)BS * 1024 * 2;          // 8.4MB
  unsigned short* vb = (unsigned short*)ws;  ws += (size_t)BS * 1024 * 2;          // 8.4MB
  unsigned short* vt = (unsigned short*)ws;  ws += (size_t)BS * 1024 * 2;          // 8.4MB
  unsigned short* ob = (unsigned short*)ws;  ws += (size_t)BS * HIDDEN * 2;        // 33.5MB

  // casts
  cast_f32_bf16<<<16384, 256, 0, stream>>>(hidden, hx);
  cast_f32_bf16<<<16384, 256, 0, stream>>>(Wq, wq);
  cast_f32_bf16<<<4096, 256, 0, stream>>>(Wk, wk);
  cast_f32_bf16<<<4096, 256, 0, stream>>>(Wv, wv);
  cast_f32_bf16<<<16384, 256, 0, stream>>>(Wo, wo);
  // projections
  gemm_bt<0><<<dim3(64, 64), 256, 0, stream>>>(hx, wq, qb, BS, HIDDEN, HIDDEN);
  gemm_bt<0><<<dim3(16, 64), 256, 0, stream>>>(hx, wk, kbf, BS, 1024, HIDDEN);
  gemm_bt<0><<<dim3(16, 64), 256, 0, stream>>>(hx, wv, vb, BS, 1024, HIDDEN);
  // rope
  rope_kernel<<<32768, 256, 0, stream>>>(qb, pos, NH);
  rope_kernel<<<8192, 256, 0, stream>>>(kbf, pos, NKV);
  // v transpose
  transpose_v<<<16384, 256, 0, stream>>>(vb, vt);
  // attention: blocks = B * NH * (S/64)
  attn_kernel<<<2048, 256, 0, stream>>>(qb, kbf, vt, ob);
  // output projection -> fp32 d_out
  gemm_bt<1><<<dim3(64, 64), 256, 0, stream>>>(ob, wo, d_out, BS, HIDDEN, HIDDEN);
}